// Round 10
// baseline (334.281 us; speedup 1.0000x reference)
//
#include <hip/hip_runtime.h>
#include <math.h>

// ARMA GNN forward: N=100000 nodes, E=1600000 edges, 64 -> 48 -> 40.
// out = log_softmax( relu( A @ (h1@W2) + h1@V2 + b2 ) ), h1 = relu( A @ (x@W1) + x@V1 + b1 )
// A = D^-1/2 (w) D^-1/2.
// R10: revert R9 slab phasing (csr re-stream cost > gather savings). Instead:
//      (a) csr compressed to 4 B/edge: (src:17 | bf15(w*dinv[dst]):15), w>0 so
//          sign dropped; (b) pull1 fused with gemm2 (agg1 tile lives in LDS,
//          saves 38.4 MB round-trip + a dispatch).

constexpr int F_IN = 64;
constexpr int HIDDEN = 48;
constexpr int N_CLASS = 40;
constexpr int CHUNK = 8192;     // edges per binning block
constexpr int BIN_SHIFT = 9;    // 512 nodes per bin
constexpr int CSR_CAP = 12288;  // LDS stash cap in build_csr (avg bin ~8163)

typedef __attribute__((ext_vector_type(8))) short bf16x8;   // 4 VGPRs
typedef __attribute__((ext_vector_type(4))) float f32x4;    // acc frag

// ---- bf16 pack helpers (RNE) ----------------------------------------------
__device__ __forceinline__ short bfr(float f) {
    unsigned u = __float_as_uint(f);
    return (short)((u + 0x7fffu + ((u >> 16) & 1u)) >> 16);
}
__device__ __forceinline__ unsigned pack_bf2(float a, float b) {
    unsigned ua = __float_as_uint(a), ub = __float_as_uint(b);
    ua = (ua + 0x7fffu + ((ua >> 16) & 1u)) >> 16;
    ub = (ub + 0x7fffu + ((ub >> 16) & 1u)) >> 16;
    return ua | (ub << 16);
}
__device__ __forceinline__ float2 unpack_bf2(unsigned u) {
    return make_float2(__uint_as_float(u << 16), __uint_as_float(u & 0xffff0000u));
}
__device__ __forceinline__ bf16x8 cvt8(float4 f0, float4 f1) {
    bf16x8 r;
    r[0] = bfr(f0.x); r[1] = bfr(f0.y); r[2] = bfr(f0.z); r[3] = bfr(f0.w);
    r[4] = bfr(f1.x); r[5] = bfr(f1.y); r[6] = bfr(f1.z); r[7] = bfr(f1.w);
    return r;
}

// ============================================================================
// MFMA layer-1 GEMM body: 64 nodes/block, 96 cols (W1|V1), K=64. Flat xWp.
// ============================================================================
__device__ __forceinline__ void mfma_gemm1_body(char* smem, const float* __restrict__ X,
                                                const float* __restrict__ W,
                                                const float* __restrict__ V,
                                                const float* __restrict__ b,
                                                unsigned* __restrict__ XWp,
                                                float* __restrict__ AGG, int N, int gb,
                                                int tid) {
    short* sWT = (short*)smem;                 // [96][64]
    float* ep = (float*)(smem + 12288);        // [64][96]
    for (int i = tid; i < 96 * 64; i += 256) {
        int c = i >> 6, k = i & 63;
        float v = (c < 48) ? W[k * 48 + c] : V[k * 48 + (c - 48)];
        sWT[i] = bfr(v);
    }
    __syncthreads();

    int lane = tid & 63, wv = tid >> 6;
    int m = lane & 15, quad = lane >> 4;
    int nb0 = gb * 64;
    int n = nb0 + wv * 16 + m;

    bf16x8 a0, a1;
    if (n < N) {
        const float4* xr = (const float4*)(X + (size_t)n * 64 + quad * 8);
        a0 = cvt8(xr[0], xr[1]);
        const float4* xr2 = (const float4*)(X + (size_t)n * 64 + 32 + quad * 8);
        a1 = cvt8(xr2[0], xr2[1]);
    } else {
        for (int j = 0; j < 8; ++j) { a0[j] = 0; a1[j] = 0; }
    }

    f32x4 acc[6];
#pragma unroll
    for (int ct = 0; ct < 6; ++ct) acc[ct] = (f32x4){0.f, 0.f, 0.f, 0.f};
#pragma unroll
    for (int ct = 0; ct < 6; ++ct) {
        bf16x8 b0 = *(const bf16x8*)(sWT + (ct * 16 + m) * 64 + quad * 8);
        bf16x8 b1 = *(const bf16x8*)(sWT + (ct * 16 + m) * 64 + 32 + quad * 8);
        acc[ct] = __builtin_amdgcn_mfma_f32_16x16x32_bf16(a0, b0, acc[ct], 0, 0, 0);
        acc[ct] = __builtin_amdgcn_mfma_f32_16x16x32_bf16(a1, b1, acc[ct], 0, 0, 0);
    }
#pragma unroll
    for (int ct = 0; ct < 6; ++ct)
#pragma unroll
        for (int r = 0; r < 4; ++r)
            ep[(wv * 16 + quad * 4 + r) * 96 + ct * 16 + m] = acc[ct][r];
    __syncthreads();
    for (int i = tid; i < 64 * 24; i += 256) {
        int r = i / 24, c2 = i - r * 24;
        int node = nb0 + r;
        if (node >= N) continue;
        float w0 = ep[r * 96 + 2 * c2], w1 = ep[r * 96 + 2 * c2 + 1];
        XWp[node * 24 + c2] = pack_bf2(w0, w1);
        float v0 = ep[r * 96 + 48 + 2 * c2], v1 = ep[r * 96 + 48 + 2 * c2 + 1];
        float2 bb = ((const float2*)b)[c2];
        ((float2*)AGG)[node * 24 + c2] = make_float2(v0 + bb.x, v1 + bb.y);
    }
}

// ---- phase A: bin counting (LDS hist -> consecutive-addr atomics) + gemm1 --
__global__ __launch_bounds__(256) void count_gemm1(
    const int* __restrict__ dst, int* __restrict__ binCnt, int E, int nCountBlocks,
    const float* __restrict__ X, const float* __restrict__ W,
    const float* __restrict__ V, const float* __restrict__ b,
    unsigned* __restrict__ XWp, float* __restrict__ AGG, int N) {
    __shared__ char smem[36864];
    if ((int)blockIdx.x < nCountBlocks) {
        int* hist = (int*)smem;
        int tid = threadIdx.x;
        hist[tid] = 0;
        __syncthreads();
        long long e0 = (long long)blockIdx.x * CHUNK;
        int M = (int)min((long long)CHUNK, (long long)E - e0);
        for (int i = tid; i < M; i += 256) atomicAdd(&hist[dst[e0 + i] >> BIN_SHIFT], 1);
        __syncthreads();
        atomicAdd(&binCnt[tid], hist[tid]);  // consecutive words -> coalesced
    } else {
        mfma_gemm1_body(smem, X, W, V, b, XWp, AGG, N,
                        (int)blockIdx.x - nCountBlocks, (int)threadIdx.x);
    }
}

// ---- phase B: exclusive scan of 256 bin counts -----------------------------
__global__ void scan_bins(const int* __restrict__ binCnt, int* __restrict__ binStart,
                          int* __restrict__ binCursor, int* __restrict__ rowPtr,
                          int E, int N) {
    __shared__ int s[256];
    int t = threadIdx.x;
    int v = binCnt[t];
    s[t] = v;
    __syncthreads();
#pragma unroll
    for (int o = 1; o < 256; o <<= 1) {
        int u = (t >= o) ? s[t - o] : 0;
        __syncthreads();
        s[t] += u;
        __syncthreads();
    }
    int excl = s[t] - v;
    binStart[t] = excl;
    binCursor[t] = excl;
    if (t == 0) {
        binStart[256] = E;
        rowPtr[N] = E;
    }
}

// ---- phase C: scatter edges into bin regions (256B runs, line-coalesced) ---
__global__ void binscatter(const int* __restrict__ src, const int* __restrict__ dst,
                           const float* __restrict__ w, int* __restrict__ binCursor,
                           int2* __restrict__ binned, int E) {
    __shared__ int sx[CHUNK];
    __shared__ int sw[CHUNK];
    __shared__ unsigned char sbin[CHUNK];
    __shared__ int hist[256];
    int tid = threadIdx.x;
    hist[tid] = 0;
    __syncthreads();
    long long e0 = (long long)blockIdx.x * CHUNK;
    int M = (int)min((long long)CHUNK, (long long)E - e0);
    for (int i = tid; i < M; i += 256) {
        int d = dst[e0 + i];
        int bn = d >> BIN_SHIFT;
        sx[i] = ((d & 511) << 17) | src[e0 + i];
        sw[i] = __float_as_int(w[e0 + i]);
        sbin[i] = (unsigned char)bn;
        atomicAdd(&hist[bn], 1);
    }
    __syncthreads();
    int base = atomicAdd(&binCursor[tid], hist[tid]);  // consecutive words -> coalesced
    __syncthreads();
    hist[tid] = base;  // reuse as global cursor
    __syncthreads();
    for (int i = tid; i < M; i += 256) {
        int p = atomicAdd(&hist[sbin[i]], 1);  // LDS atomic, cheap
        binned[p] = make_int2(sx[i], sw[i]);
    }
}

// ---- phase D: per-bin LDS counting sort -> compressed 4B CSR ---------------
// csr[e] = (src:17 << 15) | bf15(w * dinv[dst])  (w*dinv > 0, sign dropped)
__global__ __launch_bounds__(512) void build_csr(const int2* __restrict__ binned,
                                                 const int* __restrict__ binStart,
                                                 int* __restrict__ rowPtr,
                                                 float* __restrict__ dinv,
                                                 unsigned* __restrict__ csr, int N) {
    __shared__ int sx[CSR_CAP];
    __shared__ int sw[CSR_CAP];
    __shared__ int cntL[512];
    __shared__ float degL[512];  // deg sums, then dinv values
    __shared__ int scanL[512];
    int b = blockIdx.x, tid = threadIdx.x;
    int e0 = binStart[b], e1 = binStart[b + 1], M = e1 - e0;
    cntL[tid] = 0;
    degL[tid] = 0.f;
    __syncthreads();
    bool fits = (M <= CSR_CAP);
    for (int i = tid; i < M; i += 512) {
        int2 p = binned[e0 + i];
        if (fits) { sx[i] = p.x; sw[i] = p.y; }
        int dl = ((unsigned)p.x) >> 17;
        atomicAdd(&cntL[dl], 1);
        atomicAdd(&degL[dl], __int_as_float(p.y));
    }
    __syncthreads();
    int v = cntL[tid];
    scanL[tid] = v;
    __syncthreads();
#pragma unroll
    for (int o = 1; o < 512; o <<= 1) {
        int u = (tid >= o) ? scanL[tid - o] : 0;
        __syncthreads();
        scanL[tid] += u;
        __syncthreads();
    }
    int excl = scanL[tid] - v;
    int node = (b << BIN_SHIFT) + tid;
    float dg = degL[tid];
    float dv = dg > 0.f ? rsqrtf(dg) : 0.f;
    if (node < N) {
        rowPtr[node] = e0 + excl;
        dinv[node] = dv;
    }
    cntL[tid] = e0 + excl;  // reuse as global write cursor
    degL[tid] = dv;         // reuse as dinv table for write phase
    __syncthreads();
    for (int i = tid; i < M; i += 512) {
        int px, pw;
        if (fits) { px = sx[i]; pw = sw[i]; }
        else { int2 p = binned[e0 + i]; px = p.x; pw = p.y; }
        int dl = ((unsigned)px) >> 17;
        int pos = atomicAdd(&cntL[dl], 1);  // LDS atomic
        float wn = __int_as_float(pw) * degL[dl];  // fold dinv[dst] in now
        unsigned uw = __float_as_uint(wn);
        uw = (uw + 0x7fffu + ((uw >> 16) & 1u)) >> 16;  // bf16 RNE; positive -> <=0x7FFF
        csr[pos] = ((unsigned)(px & 0x1FFFF) << 15) | uw;
    }
}

// ---- xWp[n][c2] *= dinv[n]  (layer-1) --------------------------------------
__global__ void scale_xw(unsigned* __restrict__ XWp, const float* __restrict__ dinv,
                         int total) {
    int t = blockIdx.x * blockDim.x + threadIdx.x;
    if (t >= total) return;
    float dv = dinv[t / 24];
    float2 u = unpack_bf2(XWp[t]);
    XWp[t] = pack_bf2(u.x * dv, u.y * dv);
}

// ---- 4-way unrolled row accumulate, compressed csr -------------------------
template <int W>
__device__ __forceinline__ float2 row_accumC(const unsigned* __restrict__ XWp,
                                             const unsigned* __restrict__ csr, int j,
                                             int end, int c, float2 s) {
    for (; j + 4 <= end; j += 4) {
        unsigned p0 = csr[j], p1 = csr[j + 1], p2 = csr[j + 2], p3 = csr[j + 3];
        unsigned u0 = XWp[(p0 >> 15) * W + c];
        unsigned u1 = XWp[(p1 >> 15) * W + c];
        unsigned u2 = XWp[(p2 >> 15) * W + c];
        unsigned u3 = XWp[(p3 >> 15) * W + c];
        float2 x0 = unpack_bf2(u0), x1 = unpack_bf2(u1);
        float2 x2 = unpack_bf2(u2), x3 = unpack_bf2(u3);
        float n0 = __uint_as_float((p0 & 0x7FFFu) << 16);
        float n1 = __uint_as_float((p1 & 0x7FFFu) << 16);
        float n2 = __uint_as_float((p2 & 0x7FFFu) << 16);
        float n3 = __uint_as_float((p3 & 0x7FFFu) << 16);
        s.x = fmaf(x0.x, n0, s.x); s.y = fmaf(x0.y, n0, s.y);
        s.x = fmaf(x1.x, n1, s.x); s.y = fmaf(x1.y, n1, s.y);
        s.x = fmaf(x2.x, n2, s.x); s.y = fmaf(x2.y, n2, s.y);
        s.x = fmaf(x3.x, n3, s.x); s.y = fmaf(x3.y, n3, s.y);
    }
    for (; j < end; ++j) {
        unsigned p = csr[j];
        float2 xw = unpack_bf2(XWp[(p >> 15) * W + c]);
        float nr = __uint_as_float((p & 0x7FFFu) << 16);
        s.x = fmaf(xw.x, nr, s.x);
        s.y = fmaf(xw.y, nr, s.y);
    }
    return s;
}

// ============================================================================
// Fused layer-1 pull + layer-2 GEMM. 64 nodes/block.
//  phase 1: pull agg1 tile = AGG1in + sum_j xW1p[src]*nrm  -> relu -> LDS
//  phase 2: MFMA [64x48] @ [48x80 (W2|V2, K padded 64)] -> xW2p (dinv-scaled), agg2
// ============================================================================
__global__ __launch_bounds__(256) void pull1_gemm2(
    const unsigned* __restrict__ XW1p, const unsigned* __restrict__ csr,
    const int* __restrict__ rowPtr, const float* __restrict__ AGG1in,
    const float* __restrict__ W, const float* __restrict__ V,
    const float* __restrict__ b, const float* __restrict__ dinv,
    unsigned* __restrict__ XW2p, float* __restrict__ AGG2, int N) {
    __shared__ short sWT[80 * 64];  // 10 KB: W2|V2 transposed, K padded to 64
    __shared__ float sA[64 * 48];   // 12 KB: relu'd agg1 tile
    __shared__ float ep[64 * 80];   // 20 KB: epilogue
    int tid = threadIdx.x;
    for (int i = tid; i < 80 * 64; i += 256) {
        int c = i >> 6, k = i & 63;
        float v = 0.f;
        if (k < 48) v = (c < 40) ? W[k * 40 + c] : V[k * 40 + (c - 40)];
        sWT[i] = bfr(v);
    }
    int nb0 = (int)blockIdx.x * 64;
    // ---- pull phase: 64 nodes x 24 col-pairs, 6 items/thread ----
    for (int i = tid; i < 64 * 24; i += 256) {
        int nl = i / 24, c2 = i - nl * 24;
        int n = nb0 + nl;
        float2 acc = make_float2(0.f, 0.f);
        if (n < N) {
            acc = ((const float2*)AGG1in)[n * 24 + c2];
            acc = row_accumC<24>(XW1p, csr, rowPtr[n], rowPtr[n + 1], c2, acc);
        }
        sA[nl * 48 + 2 * c2] = fmaxf(acc.x, 0.f);
        sA[nl * 48 + 2 * c2 + 1] = fmaxf(acc.y, 0.f);
    }
    __syncthreads();
    // ---- gemm2 phase ----
    int lane = tid & 63, wv = tid >> 6;
    int m = lane & 15, quad = lane >> 4;
    bf16x8 a0, a1;
    {
        const float* ar = sA + (wv * 16 + m) * 48;
        float4 f0 = *(const float4*)(ar + quad * 8);
        float4 f1 = *(const float4*)(ar + quad * 8 + 4);
        a0 = cvt8(f0, f1);
        if (quad < 2) {
            float4 g0 = *(const float4*)(ar + 32 + quad * 8);
            float4 g1 = *(const float4*)(ar + 32 + quad * 8 + 4);
            a1 = cvt8(g0, g1);
        } else {
            for (int j = 0; j < 8; ++j) a1[j] = 0;
        }
    }
    f32x4 acc[5];
#pragma unroll
    for (int ct = 0; ct < 5; ++ct) acc[ct] = (f32x4){0.f, 0.f, 0.f, 0.f};
#pragma unroll
    for (int ct = 0; ct < 5; ++ct) {
        bf16x8 b0 = *(const bf16x8*)(sWT + (ct * 16 + m) * 64 + quad * 8);
        bf16x8 b1 = *(const bf16x8*)(sWT + (ct * 16 + m) * 64 + 32 + quad * 8);
        acc[ct] = __builtin_amdgcn_mfma_f32_16x16x32_bf16(a0, b0, acc[ct], 0, 0, 0);
        acc[ct] = __builtin_amdgcn_mfma_f32_16x16x32_bf16(a1, b1, acc[ct], 0, 0, 0);
    }
#pragma unroll
    for (int ct = 0; ct < 5; ++ct)
#pragma unroll
        for (int r = 0; r < 4; ++r)
            ep[(wv * 16 + quad * 4 + r) * 80 + ct * 16 + m] = acc[ct][r];
    __syncthreads();
    for (int i = tid; i < 64 * 20; i += 256) {
        int r = i / 20, c2 = i - r * 20;
        int node = nb0 + r;
        if (node >= N) continue;
        float dv = dinv[node];
        float w0 = ep[r * 80 + 2 * c2], w1 = ep[r * 80 + 2 * c2 + 1];
        XW2p[node * 20 + c2] = pack_bf2(w0 * dv, w1 * dv);
        float v0 = ep[r * 80 + 40 + 2 * c2], v1 = ep[r * 80 + 40 + 2 * c2 + 1];
        float2 bb = ((const float2*)b)[c2];
        ((float2*)AGG2)[node * 20 + c2] = make_float2(v0 + bb.x, v1 + bb.y);
    }
}

// ---- layer-2 pull fused with log_softmax(relu(.)) --------------------------
// block = 320 threads = 16 nodes x 20 col-pairs.
__global__ __launch_bounds__(320) void pull_ls(const unsigned* __restrict__ XWp,
                                               const unsigned* __restrict__ csr,
                                               const int* __restrict__ rowPtr,
                                               const float* __restrict__ AGGin,
                                               float* __restrict__ out, int N) {
    constexpr int C2 = N_CLASS / 2;  // 20
    __shared__ float2 sbuf[16 * C2];
    __shared__ float sl[16];
    int tid = threadIdx.x;
    int nl = tid / C2, c2 = tid - nl * C2;
    int n = blockIdx.x * 16 + nl;
    float2 s = make_float2(0.f, 0.f);
    if (n < N) {
        s = ((const float2*)AGGin)[n * C2 + c2];
        s = row_accumC<C2>(XWp, csr, rowPtr[n], rowPtr[n + 1], c2, s);
    }
    sbuf[tid] = s;
    __syncthreads();
    if (tid < 16) {
        const float2* row = sbuf + tid * C2;
        float m = 0.f;  // relu floor
        for (int k = 0; k < C2; ++k) {
            float2 v = row[k];
            m = fmaxf(m, fmaxf(v.x, v.y));
        }
        float sum = 0.f;
        for (int k = 0; k < C2; ++k) {
            float2 v = row[k];
            sum += expf(fmaxf(v.x, 0.f) - m) + expf(fmaxf(v.y, 0.f) - m);
        }
        sl[tid] = m + logf(sum);
    }
    __syncthreads();
    if (n < N) {
        float l = sl[nl];
        ((float2*)out)[n * C2 + c2] =
            make_float2(fmaxf(s.x, 0.f) - l, fmaxf(s.y, 0.f) - l);
    }
}

extern "C" void kernel_launch(void* const* d_in, const int* in_sizes, int n_in,
                              void* d_out, int out_size, void* d_ws, size_t ws_size,
                              hipStream_t stream) {
    const float* x  = (const float*)d_in[0];
    const int*   ei = (const int*)d_in[1];
    const float* ew = (const float*)d_in[2];
    const float* W1 = (const float*)d_in[3];
    const float* V1 = (const float*)d_in[4];
    const float* b1 = (const float*)d_in[5];
    const float* W2 = (const float*)d_in[6];
    const float* V2 = (const float*)d_in[7];
    const float* b2 = (const float*)d_in[8];
    float* out = (float*)d_out;

    const int N = in_sizes[0] / F_IN;
    const int E = in_sizes[2];
    const int* src = ei;
    const int* dst = ei + E;

    char* ws = (char*)d_ws;
    size_t off = 0;
    auto carve = [&](size_t bytes) {
        void* p = ws + off;
        off = (off + bytes + 255) & ~size_t(255);
        return p;
    };
    int*      binCnt    = (int*)carve(256 * 4);
    int*      binStart  = (int*)carve(257 * 4);
    int*      binCursor = (int*)carve(256 * 4);
    int*      rowPtr    = (int*)carve((size_t)(N + 1) * 4);
    float*    dinv      = (float*)carve((size_t)N * 4);
    int2*     binned    = (int2*)carve((size_t)E * 8);
    unsigned* csr       = (unsigned*)carve((size_t)E * 4);        // compressed
    unsigned* xW1p      = (unsigned*)carve((size_t)N * 24 * 4);   // bf16x2 flat
    unsigned* xW2p      = (unsigned*)carve((size_t)N * 20 * 4);   // separate (no alias)
    float*    agg1      = (float*)carve((size_t)N * HIDDEN * 4);  // V1-part only
    float*    agg2      = (float*)carve((size_t)N * N_CLASS * 4);

    const int B = 256;
    auto cdiv = [](long long a, long long b) { return (int)((a + b - 1) / b); };
    const int nChunks = cdiv(E, CHUNK);
    const int nBins = (N + (1 << BIN_SHIFT) - 1) >> BIN_SHIFT;
    const int nGemmBlocks = cdiv(N, 64);

    hipMemsetAsync(binCnt, 0, 256 * 4, stream);

    count_gemm1<<<nChunks + nGemmBlocks, B, 0, stream>>>(dst, binCnt, E, nChunks,
                                                         x, W1, V1, b1, xW1p, agg1, N);
    scan_bins<<<1, 256, 0, stream>>>(binCnt, binStart, binCursor, rowPtr, E, N);
    binscatter<<<nChunks, B, 0, stream>>>(src, dst, ew, binCursor, binned, E);
    build_csr<<<nBins, 512, 0, stream>>>(binned, binStart, rowPtr, dinv, csr, N);

    scale_xw<<<cdiv((long long)N * 24, B), B, 0, stream>>>(xW1p, dinv, N * 24);

    pull1_gemm2<<<nGemmBlocks, B, 0, stream>>>(xW1p, csr, rowPtr, agg1,
                                               W2, V2, b2, dinv, xW2p, agg2, N);

    pull_ls<<<cdiv(N, 16), 320, 0, stream>>>(xW2p, csr, rowPtr, agg2, out, N);
}

// Round 11
// 287.026 us; speedup vs baseline: 1.1646x; 1.1646x over previous
//
#include <hip/hip_runtime.h>
#include <math.h>

// ARMA GNN forward: N=100000 nodes, E=1600000 edges, 64 -> 48 -> 40.
// out = log_softmax( relu( A @ (h1@W2) + h1@V2 + b2 ) ), h1 = relu( A @ (x@W1) + x@V1 + b1 )
// A = D^-1/2 (w) D^-1/2.
// R11: R8 skeleton (skinny high-occupancy pulls, fused count+gemm1) +
//      (a) 4B compressed csr (src:17|bf15(w*dinv[dst]));
//      (b) pull_agg emits relu'd bf16 h1 (9.6MB) -> gemm2 loads bf16 A directly.
//      R10 lesson: never fuse latency-bound gathers into LDS-heavy kernels.

constexpr int F_IN = 64;
constexpr int HIDDEN = 48;
constexpr int N_CLASS = 40;
constexpr int CHUNK = 8192;     // edges per binning block
constexpr int BIN_SHIFT = 9;    // 512 nodes per bin
constexpr int CSR_CAP = 12288;  // LDS stash cap in build_csr (avg bin ~8163)

typedef __attribute__((ext_vector_type(8))) short bf16x8;   // 4 VGPRs
typedef __attribute__((ext_vector_type(4))) float f32x4;    // acc frag

// ---- bf16 pack helpers (RNE) ----------------------------------------------
__device__ __forceinline__ short bfr(float f) {
    unsigned u = __float_as_uint(f);
    return (short)((u + 0x7fffu + ((u >> 16) & 1u)) >> 16);
}
__device__ __forceinline__ unsigned pack_bf2(float a, float b) {
    unsigned ua = __float_as_uint(a), ub = __float_as_uint(b);
    ua = (ua + 0x7fffu + ((ua >> 16) & 1u)) >> 16;
    ub = (ub + 0x7fffu + ((ub >> 16) & 1u)) >> 16;
    return ua | (ub << 16);
}
__device__ __forceinline__ float2 unpack_bf2(unsigned u) {
    return make_float2(__uint_as_float(u << 16), __uint_as_float(u & 0xffff0000u));
}
__device__ __forceinline__ bf16x8 cvt8(float4 f0, float4 f1) {
    bf16x8 r;
    r[0] = bfr(f0.x); r[1] = bfr(f0.y); r[2] = bfr(f0.z); r[3] = bfr(f0.w);
    r[4] = bfr(f1.x); r[5] = bfr(f1.y); r[6] = bfr(f1.z); r[7] = bfr(f1.w);
    return r;
}

// ============================================================================
// MFMA layer-1 GEMM body: 64 nodes/block, 96 cols (W1|V1), K=64. Flat xWp.
// ============================================================================
__device__ __forceinline__ void mfma_gemm1_body(char* smem, const float* __restrict__ X,
                                                const float* __restrict__ W,
                                                const float* __restrict__ V,
                                                const float* __restrict__ b,
                                                unsigned* __restrict__ XWp,
                                                float* __restrict__ AGG, int N, int gb,
                                                int tid) {
    short* sWT = (short*)smem;                 // [96][64]
    float* ep = (float*)(smem + 12288);        // [64][96]
    for (int i = tid; i < 96 * 64; i += 256) {
        int c = i >> 6, k = i & 63;
        float v = (c < 48) ? W[k * 48 + c] : V[k * 48 + (c - 48)];
        sWT[i] = bfr(v);
    }
    __syncthreads();

    int lane = tid & 63, wv = tid >> 6;
    int m = lane & 15, quad = lane >> 4;
    int nb0 = gb * 64;
    int n = nb0 + wv * 16 + m;

    bf16x8 a0, a1;
    if (n < N) {
        const float4* xr = (const float4*)(X + (size_t)n * 64 + quad * 8);
        a0 = cvt8(xr[0], xr[1]);
        const float4* xr2 = (const float4*)(X + (size_t)n * 64 + 32 + quad * 8);
        a1 = cvt8(xr2[0], xr2[1]);
    } else {
        for (int j = 0; j < 8; ++j) { a0[j] = 0; a1[j] = 0; }
    }

    f32x4 acc[6];
#pragma unroll
    for (int ct = 0; ct < 6; ++ct) acc[ct] = (f32x4){0.f, 0.f, 0.f, 0.f};
#pragma unroll
    for (int ct = 0; ct < 6; ++ct) {
        bf16x8 b0 = *(const bf16x8*)(sWT + (ct * 16 + m) * 64 + quad * 8);
        bf16x8 b1 = *(const bf16x8*)(sWT + (ct * 16 + m) * 64 + 32 + quad * 8);
        acc[ct] = __builtin_amdgcn_mfma_f32_16x16x32_bf16(a0, b0, acc[ct], 0, 0, 0);
        acc[ct] = __builtin_amdgcn_mfma_f32_16x16x32_bf16(a1, b1, acc[ct], 0, 0, 0);
    }
#pragma unroll
    for (int ct = 0; ct < 6; ++ct)
#pragma unroll
        for (int r = 0; r < 4; ++r)
            ep[(wv * 16 + quad * 4 + r) * 96 + ct * 16 + m] = acc[ct][r];
    __syncthreads();
    for (int i = tid; i < 64 * 24; i += 256) {
        int r = i / 24, c2 = i - r * 24;
        int node = nb0 + r;
        if (node >= N) continue;
        float w0 = ep[r * 96 + 2 * c2], w1 = ep[r * 96 + 2 * c2 + 1];
        XWp[node * 24 + c2] = pack_bf2(w0, w1);
        float v0 = ep[r * 96 + 48 + 2 * c2], v1 = ep[r * 96 + 48 + 2 * c2 + 1];
        float2 bb = ((const float2*)b)[c2];
        ((float2*)AGG)[node * 24 + c2] = make_float2(v0 + bb.x, v1 + bb.y);
    }
}

// ---- phase A: bin counting (LDS hist -> consecutive-addr atomics) + gemm1 --
__global__ __launch_bounds__(256) void count_gemm1(
    const int* __restrict__ dst, int* __restrict__ binCnt, int E, int nCountBlocks,
    const float* __restrict__ X, const float* __restrict__ W,
    const float* __restrict__ V, const float* __restrict__ b,
    unsigned* __restrict__ XWp, float* __restrict__ AGG, int N) {
    __shared__ char smem[36864];
    if ((int)blockIdx.x < nCountBlocks) {
        int* hist = (int*)smem;
        int tid = threadIdx.x;
        hist[tid] = 0;
        __syncthreads();
        long long e0 = (long long)blockIdx.x * CHUNK;
        int M = (int)min((long long)CHUNK, (long long)E - e0);
        for (int i = tid; i < M; i += 256) atomicAdd(&hist[dst[e0 + i] >> BIN_SHIFT], 1);
        __syncthreads();
        atomicAdd(&binCnt[tid], hist[tid]);  // consecutive words -> coalesced
    } else {
        mfma_gemm1_body(smem, X, W, V, b, XWp, AGG, N,
                        (int)blockIdx.x - nCountBlocks, (int)threadIdx.x);
    }
}

// ---- phase B: exclusive scan of 256 bin counts -----------------------------
__global__ void scan_bins(const int* __restrict__ binCnt, int* __restrict__ binStart,
                          int* __restrict__ binCursor, int* __restrict__ rowPtr,
                          int E, int N) {
    __shared__ int s[256];
    int t = threadIdx.x;
    int v = binCnt[t];
    s[t] = v;
    __syncthreads();
#pragma unroll
    for (int o = 1; o < 256; o <<= 1) {
        int u = (t >= o) ? s[t - o] : 0;
        __syncthreads();
        s[t] += u;
        __syncthreads();
    }
    int excl = s[t] - v;
    binStart[t] = excl;
    binCursor[t] = excl;
    if (t == 0) {
        binStart[256] = E;
        rowPtr[N] = E;
    }
}

// ---- phase C: scatter edges into bin regions (256B runs, line-coalesced) ---
__global__ void binscatter(const int* __restrict__ src, const int* __restrict__ dst,
                           const float* __restrict__ w, int* __restrict__ binCursor,
                           int2* __restrict__ binned, int E) {
    __shared__ int sx[CHUNK];
    __shared__ int sw[CHUNK];
    __shared__ unsigned char sbin[CHUNK];
    __shared__ int hist[256];
    int tid = threadIdx.x;
    hist[tid] = 0;
    __syncthreads();
    long long e0 = (long long)blockIdx.x * CHUNK;
    int M = (int)min((long long)CHUNK, (long long)E - e0);
    for (int i = tid; i < M; i += 256) {
        int d = dst[e0 + i];
        int bn = d >> BIN_SHIFT;
        sx[i] = ((d & 511) << 17) | src[e0 + i];
        sw[i] = __float_as_int(w[e0 + i]);
        sbin[i] = (unsigned char)bn;
        atomicAdd(&hist[bn], 1);
    }
    __syncthreads();
    int base = atomicAdd(&binCursor[tid], hist[tid]);  // consecutive words -> coalesced
    __syncthreads();
    hist[tid] = base;  // reuse as global cursor
    __syncthreads();
    for (int i = tid; i < M; i += 256) {
        int p = atomicAdd(&hist[sbin[i]], 1);  // LDS atomic, cheap
        binned[p] = make_int2(sx[i], sw[i]);
    }
}

// ---- phase D: per-bin LDS counting sort -> compressed 4B CSR ---------------
// csr[e] = (src:17 << 15) | bf15(w * dinv[dst])  (w*dinv > 0, sign dropped)
__global__ __launch_bounds__(512) void build_csr(const int2* __restrict__ binned,
                                                 const int* __restrict__ binStart,
                                                 int* __restrict__ rowPtr,
                                                 float* __restrict__ dinv,
                                                 unsigned* __restrict__ csr, int N) {
    __shared__ int sx[CSR_CAP];
    __shared__ int sw[CSR_CAP];
    __shared__ int cntL[512];
    __shared__ float degL[512];  // deg sums, then dinv values
    __shared__ int scanL[512];
    int b = blockIdx.x, tid = threadIdx.x;
    int e0 = binStart[b], e1 = binStart[b + 1], M = e1 - e0;
    cntL[tid] = 0;
    degL[tid] = 0.f;
    __syncthreads();
    bool fits = (M <= CSR_CAP);
    for (int i = tid; i < M; i += 512) {
        int2 p = binned[e0 + i];
        if (fits) { sx[i] = p.x; sw[i] = p.y; }
        int dl = ((unsigned)p.x) >> 17;
        atomicAdd(&cntL[dl], 1);
        atomicAdd(&degL[dl], __int_as_float(p.y));
    }
    __syncthreads();
    int v = cntL[tid];
    scanL[tid] = v;
    __syncthreads();
#pragma unroll
    for (int o = 1; o < 512; o <<= 1) {
        int u = (tid >= o) ? scanL[tid - o] : 0;
        __syncthreads();
        scanL[tid] += u;
        __syncthreads();
    }
    int excl = scanL[tid] - v;
    int node = (b << BIN_SHIFT) + tid;
    float dg = degL[tid];
    float dv = dg > 0.f ? rsqrtf(dg) : 0.f;
    if (node < N) {
        rowPtr[node] = e0 + excl;
        dinv[node] = dv;
    }
    cntL[tid] = e0 + excl;  // reuse as global write cursor
    degL[tid] = dv;         // reuse as dinv table for write phase
    __syncthreads();
    for (int i = tid; i < M; i += 512) {
        int px, pw;
        if (fits) { px = sx[i]; pw = sw[i]; }
        else { int2 p = binned[e0 + i]; px = p.x; pw = p.y; }
        int dl = ((unsigned)px) >> 17;
        int pos = atomicAdd(&cntL[dl], 1);  // LDS atomic
        float wn = __int_as_float(pw) * degL[dl];  // fold dinv[dst] in now
        unsigned uw = __float_as_uint(wn);
        uw = (uw + 0x7fffu + ((uw >> 16) & 1u)) >> 16;  // bf16 RNE; positive -> <=0x7FFF
        csr[pos] = ((unsigned)(px & 0x1FFFF) << 15) | uw;
    }
}

// ---- xWp[n][c2] *= dinv[n]  (layer-1) --------------------------------------
__global__ void scale_xw(unsigned* __restrict__ XWp, const float* __restrict__ dinv,
                         int total) {
    int t = blockIdx.x * blockDim.x + threadIdx.x;
    if (t >= total) return;
    float dv = dinv[t / 24];
    float2 u = unpack_bf2(XWp[t]);
    XWp[t] = pack_bf2(u.x * dv, u.y * dv);
}

// ---- 4-way unrolled row accumulate, compressed csr -------------------------
template <int W>
__device__ __forceinline__ float2 row_accumC(const unsigned* __restrict__ XWp,
                                             const unsigned* __restrict__ csr, int j,
                                             int end, int c, float2 s) {
    for (; j + 4 <= end; j += 4) {
        unsigned p0 = csr[j], p1 = csr[j + 1], p2 = csr[j + 2], p3 = csr[j + 3];
        unsigned u0 = XWp[(p0 >> 15) * W + c];
        unsigned u1 = XWp[(p1 >> 15) * W + c];
        unsigned u2 = XWp[(p2 >> 15) * W + c];
        unsigned u3 = XWp[(p3 >> 15) * W + c];
        float2 x0 = unpack_bf2(u0), x1 = unpack_bf2(u1);
        float2 x2 = unpack_bf2(u2), x3 = unpack_bf2(u3);
        float n0 = __uint_as_float((p0 & 0x7FFFu) << 16);
        float n1 = __uint_as_float((p1 & 0x7FFFu) << 16);
        float n2 = __uint_as_float((p2 & 0x7FFFu) << 16);
        float n3 = __uint_as_float((p3 & 0x7FFFu) << 16);
        s.x = fmaf(x0.x, n0, s.x); s.y = fmaf(x0.y, n0, s.y);
        s.x = fmaf(x1.x, n1, s.x); s.y = fmaf(x1.y, n1, s.y);
        s.x = fmaf(x2.x, n2, s.x); s.y = fmaf(x2.y, n2, s.y);
        s.x = fmaf(x3.x, n3, s.x); s.y = fmaf(x3.y, n3, s.y);
    }
    for (; j < end; ++j) {
        unsigned p = csr[j];
        float2 xw = unpack_bf2(XWp[(p >> 15) * W + c]);
        float nr = __uint_as_float((p & 0x7FFFu) << 16);
        s.x = fmaf(xw.x, nr, s.x);
        s.y = fmaf(xw.y, nr, s.y);
    }
    return s;
}

// ---- layer-1 pull: h1[n] = relu(AGGin[n] + sum_j xWp[src_j]*nrm_j) as bf16 -
// skinny: 0 LDS, low VGPR -> max occupancy for gather latency hiding.
__global__ void pull_agg(const unsigned* __restrict__ XWp, const unsigned* __restrict__ csr,
                         const int* __restrict__ rowPtr, const float* __restrict__ AGGin,
                         unsigned* __restrict__ H1p, int N) {
    constexpr int C2 = HIDDEN / 2;  // 24
    int t = blockIdx.x * blockDim.x + threadIdx.x;
    if (t >= N * C2) return;
    int n = t / C2, c2 = t - n * C2;
    float2 s = ((const float2*)AGGin)[t];
    s = row_accumC<C2>(XWp, csr, rowPtr[n], rowPtr[n + 1], c2, s);
    H1p[t] = pack_bf2(fmaxf(s.x, 0.f), fmaxf(s.y, 0.f));  // relu'd bf16 h1
}

// ============================================================================
// MFMA layer-2 GEMM: 64 nodes/block, 80 cols (W2|V2), K=48 zero-padded to 64.
// A = h1 already relu'd bf16 -> direct 16B fragment loads. xW2p dinv-scaled.
// ============================================================================
__global__ __launch_bounds__(256) void gemm2_kernel(
    const short* __restrict__ H1, const float* __restrict__ W,
    const float* __restrict__ V, const float* __restrict__ b,
    const float* __restrict__ dinv, unsigned* __restrict__ XWp,
    float* __restrict__ AGG, int N) {
    __shared__ char smem[30720];
    short* sWT = (short*)smem;            // [80][64], k>=48 zero
    float* ep = (float*)(smem + 10240);   // [64][80]
    int tid = threadIdx.x;
    for (int i = tid; i < 80 * 64; i += 256) {
        int c = i >> 6, k = i & 63;
        float v = 0.f;
        if (k < 48) v = (c < 40) ? W[k * 40 + c] : V[k * 40 + (c - 40)];
        sWT[i] = bfr(v);
    }
    __syncthreads();

    int lane = tid & 63, wv = tid >> 6;
    int m = lane & 15, quad = lane >> 4;
    int nb0 = (int)blockIdx.x * 64;
    int n = nb0 + wv * 16 + m;

    bf16x8 a0, a1;
    if (n < N) {
        a0 = *(const bf16x8*)(H1 + (size_t)n * 48 + quad * 8);
        if (quad < 2) {
            a1 = *(const bf16x8*)(H1 + (size_t)n * 48 + 32 + quad * 8);
        } else {
            for (int j = 0; j < 8; ++j) a1[j] = 0;
        }
    } else {
        for (int j = 0; j < 8; ++j) { a0[j] = 0; a1[j] = 0; }
    }

    f32x4 acc[5];
#pragma unroll
    for (int ct = 0; ct < 5; ++ct) acc[ct] = (f32x4){0.f, 0.f, 0.f, 0.f};
#pragma unroll
    for (int ct = 0; ct < 5; ++ct) {
        bf16x8 b0 = *(const bf16x8*)(sWT + (ct * 16 + m) * 64 + quad * 8);
        bf16x8 b1 = *(const bf16x8*)(sWT + (ct * 16 + m) * 64 + 32 + quad * 8);
        acc[ct] = __builtin_amdgcn_mfma_f32_16x16x32_bf16(a0, b0, acc[ct], 0, 0, 0);
        acc[ct] = __builtin_amdgcn_mfma_f32_16x16x32_bf16(a1, b1, acc[ct], 0, 0, 0);
    }
#pragma unroll
    for (int ct = 0; ct < 5; ++ct)
#pragma unroll
        for (int r = 0; r < 4; ++r)
            ep[(wv * 16 + quad * 4 + r) * 80 + ct * 16 + m] = acc[ct][r];
    __syncthreads();
    for (int i = tid; i < 64 * 20; i += 256) {
        int r = i / 20, c2 = i - r * 20;
        int node = nb0 + r;
        if (node >= N) continue;
        float dv = dinv[node];
        float w0 = ep[r * 80 + 2 * c2], w1 = ep[r * 80 + 2 * c2 + 1];
        XWp[node * 20 + c2] = pack_bf2(w0 * dv, w1 * dv);
        float v0 = ep[r * 80 + 40 + 2 * c2], v1 = ep[r * 80 + 40 + 2 * c2 + 1];
        float2 bb = ((const float2*)b)[c2];
        ((float2*)AGG)[node * 20 + c2] = make_float2(v0 + bb.x, v1 + bb.y);
    }
}

// ---- layer-2 pull fused with log_softmax(relu(.)) --------------------------
// block = 320 threads = 16 nodes x 20 col-pairs.
__global__ __launch_bounds__(320) void pull_ls(const unsigned* __restrict__ XWp,
                                               const unsigned* __restrict__ csr,
                                               const int* __restrict__ rowPtr,
                                               const float* __restrict__ AGGin,
                                               float* __restrict__ out, int N) {
    constexpr int C2 = N_CLASS / 2;  // 20
    __shared__ float2 sbuf[16 * C2];
    __shared__ float sl[16];
    int tid = threadIdx.x;
    int nl = tid / C2, c2 = tid - nl * C2;
    int n = blockIdx.x * 16 + nl;
    float2 s = make_float2(0.f, 0.f);
    if (n < N) {
        s = ((const float2*)AGGin)[n * C2 + c2];
        s = row_accumC<C2>(XWp, csr, rowPtr[n], rowPtr[n + 1], c2, s);
    }
    sbuf[tid] = s;
    __syncthreads();
    if (tid < 16) {
        const float2* row = sbuf + tid * C2;
        float m = 0.f;  // relu floor
        for (int k = 0; k < C2; ++k) {
            float2 v = row[k];
            m = fmaxf(m, fmaxf(v.x, v.y));
        }
        float sum = 0.f;
        for (int k = 0; k < C2; ++k) {
            float2 v = row[k];
            sum += expf(fmaxf(v.x, 0.f) - m) + expf(fmaxf(v.y, 0.f) - m);
        }
        sl[tid] = m + logf(sum);
    }
    __syncthreads();
    if (n < N) {
        float l = sl[nl];
        ((float2*)out)[n * C2 + c2] =
            make_float2(fmaxf(s.x, 0.f) - l, fmaxf(s.y, 0.f) - l);
    }
}

extern "C" void kernel_launch(void* const* d_in, const int* in_sizes, int n_in,
                              void* d_out, int out_size, void* d_ws, size_t ws_size,
                              hipStream_t stream) {
    const float* x  = (const float*)d_in[0];
    const int*   ei = (const int*)d_in[1];
    const float* ew = (const float*)d_in[2];
    const float* W1 = (const float*)d_in[3];
    const float* V1 = (const float*)d_in[4];
    const float* b1 = (const float*)d_in[5];
    const float* W2 = (const float*)d_in[6];
    const float* V2 = (const float*)d_in[7];
    const float* b2 = (const float*)d_in[8];
    float* out = (float*)d_out;

    const int N = in_sizes[0] / F_IN;
    const int E = in_sizes[2];
    const int* src = ei;
    const int* dst = ei + E;

    char* ws = (char*)d_ws;
    size_t off = 0;
    auto carve = [&](size_t bytes) {
        void* p = ws + off;
        off = (off + bytes + 255) & ~size_t(255);
        return p;
    };
    int*      binCnt    = (int*)carve(256 * 4);
    int*      binStart  = (int*)carve(257 * 4);
    int*      binCursor = (int*)carve(256 * 4);
    int*      rowPtr    = (int*)carve((size_t)(N + 1) * 4);
    float*    dinv      = (float*)carve((size_t)N * 4);
    int2*     binned    = (int2*)carve((size_t)E * 8);
    unsigned* csr       = (unsigned*)carve((size_t)E * 4);        // compressed 4B
    unsigned* xW1p      = (unsigned*)carve((size_t)N * 24 * 4);   // bf16x2 flat
    float*    agg1      = (float*)carve((size_t)N * HIDDEN * 4);  // fp32 V1-part
    unsigned* h1p       = (unsigned*)carve((size_t)N * 24 * 4);   // relu'd bf16 h1
    unsigned* xW2p      = (unsigned*)carve((size_t)N * 20 * 4);
    float*    agg2      = (float*)carve((size_t)N * N_CLASS * 4);

    const int B = 256;
    auto cdiv = [](long long a, long long b) { return (int)((a + b - 1) / b); };
    const int nChunks = cdiv(E, CHUNK);
    const int nBins = (N + (1 << BIN_SHIFT) - 1) >> BIN_SHIFT;
    const int nGemmBlocks = cdiv(N, 64);

    hipMemsetAsync(binCnt, 0, 256 * 4, stream);

    count_gemm1<<<nChunks + nGemmBlocks, B, 0, stream>>>(dst, binCnt, E, nChunks,
                                                         x, W1, V1, b1, xW1p, agg1, N);
    scan_bins<<<1, 256, 0, stream>>>(binCnt, binStart, binCursor, rowPtr, E, N);
    binscatter<<<nChunks, B, 0, stream>>>(src, dst, ew, binCursor, binned, E);
    build_csr<<<nBins, 512, 0, stream>>>(binned, binStart, rowPtr, dinv, csr, N);

    scale_xw<<<cdiv((long long)N * 24, B), B, 0, stream>>>(xW1p, dinv, N * 24);

    pull_agg<<<cdiv((long long)N * 24, B), B, 0, stream>>>(xW1p, csr, rowPtr,
                                                           agg1, h1p, N);

    gemm2_kernel<<<nGemmBlocks, B, 0, stream>>>((const short*)h1p, W2, V2, b2,
                                                dinv, xW2p, agg2, N);

    pull_ls<<<cdiv(N, 16), 320, 0, stream>>>(xW2p, csr, rowPtr, agg2, out, N);
}

// Round 12
// 278.331 us; speedup vs baseline: 1.2010x; 1.0312x over previous
//
#include <hip/hip_runtime.h>
#include <math.h>

// ARMA GNN forward: N=100000 nodes, E=1600000 edges, 64 -> 48 -> 40.
// out = log_softmax( relu( A @ (h1@W2) + h1@V2 + b2 ) ), h1 = relu( A @ (x@W1) + x@V1 + b1 )
// A = D^-1/2 (w) D^-1/2.
// R12: pull VALU cut: 2 u32 (8B) gathers per thread (12/10 threads per node),
//      aligned uint4 csr loads (1 dwordx4 per 4 edges), agg1/agg2 init buffers
//      packed bf16 (halves stream traffic). Skeleton unchanged from R11.

constexpr int F_IN = 64;
constexpr int HIDDEN = 48;
constexpr int N_CLASS = 40;
constexpr int CHUNK = 8192;     // edges per binning block
constexpr int BIN_SHIFT = 9;    // 512 nodes per bin
constexpr int CSR_CAP = 12288;  // LDS stash cap in build_csr (avg bin ~8163)

typedef __attribute__((ext_vector_type(8))) short bf16x8;   // 4 VGPRs
typedef __attribute__((ext_vector_type(4))) float f32x4;    // acc frag

// ---- bf16 pack helpers (RNE) ----------------------------------------------
__device__ __forceinline__ short bfr(float f) {
    unsigned u = __float_as_uint(f);
    return (short)((u + 0x7fffu + ((u >> 16) & 1u)) >> 16);
}
__device__ __forceinline__ unsigned pack_bf2(float a, float b) {
    unsigned ua = __float_as_uint(a), ub = __float_as_uint(b);
    ua = (ua + 0x7fffu + ((ua >> 16) & 1u)) >> 16;
    ub = (ub + 0x7fffu + ((ub >> 16) & 1u)) >> 16;
    return ua | (ub << 16);
}
__device__ __forceinline__ float2 unpack_bf2(unsigned u) {
    return make_float2(__uint_as_float(u << 16), __uint_as_float(u & 0xffff0000u));
}
__device__ __forceinline__ bf16x8 cvt8(float4 f0, float4 f1) {
    bf16x8 r;
    r[0] = bfr(f0.x); r[1] = bfr(f0.y); r[2] = bfr(f0.z); r[3] = bfr(f0.w);
    r[4] = bfr(f1.x); r[5] = bfr(f1.y); r[6] = bfr(f1.z); r[7] = bfr(f1.w);
    return r;
}

// ============================================================================
// MFMA layer-1 GEMM body: 64 nodes/block, 96 cols (W1|V1), K=64.
// xW1p flat bf16x2; V-part (agg1 init) packed bf16x2 too.
// ============================================================================
__device__ __forceinline__ void mfma_gemm1_body(char* smem, const float* __restrict__ X,
                                                const float* __restrict__ W,
                                                const float* __restrict__ V,
                                                const float* __restrict__ b,
                                                unsigned* __restrict__ XWp,
                                                unsigned* __restrict__ AGGp, int N,
                                                int gb, int tid) {
    short* sWT = (short*)smem;                 // [96][64]
    float* ep = (float*)(smem + 12288);        // [64][96]
    for (int i = tid; i < 96 * 64; i += 256) {
        int c = i >> 6, k = i & 63;
        float v = (c < 48) ? W[k * 48 + c] : V[k * 48 + (c - 48)];
        sWT[i] = bfr(v);
    }
    __syncthreads();

    int lane = tid & 63, wv = tid >> 6;
    int m = lane & 15, quad = lane >> 4;
    int nb0 = gb * 64;
    int n = nb0 + wv * 16 + m;

    bf16x8 a0, a1;
    if (n < N) {
        const float4* xr = (const float4*)(X + (size_t)n * 64 + quad * 8);
        a0 = cvt8(xr[0], xr[1]);
        const float4* xr2 = (const float4*)(X + (size_t)n * 64 + 32 + quad * 8);
        a1 = cvt8(xr2[0], xr2[1]);
    } else {
        for (int j = 0; j < 8; ++j) { a0[j] = 0; a1[j] = 0; }
    }

    f32x4 acc[6];
#pragma unroll
    for (int ct = 0; ct < 6; ++ct) acc[ct] = (f32x4){0.f, 0.f, 0.f, 0.f};
#pragma unroll
    for (int ct = 0; ct < 6; ++ct) {
        bf16x8 b0 = *(const bf16x8*)(sWT + (ct * 16 + m) * 64 + quad * 8);
        bf16x8 b1 = *(const bf16x8*)(sWT + (ct * 16 + m) * 64 + 32 + quad * 8);
        acc[ct] = __builtin_amdgcn_mfma_f32_16x16x32_bf16(a0, b0, acc[ct], 0, 0, 0);
        acc[ct] = __builtin_amdgcn_mfma_f32_16x16x32_bf16(a1, b1, acc[ct], 0, 0, 0);
    }
#pragma unroll
    for (int ct = 0; ct < 6; ++ct)
#pragma unroll
        for (int r = 0; r < 4; ++r)
            ep[(wv * 16 + quad * 4 + r) * 96 + ct * 16 + m] = acc[ct][r];
    __syncthreads();
    for (int i = tid; i < 64 * 24; i += 256) {
        int r = i / 24, c2 = i - r * 24;
        int node = nb0 + r;
        if (node >= N) continue;
        float w0 = ep[r * 96 + 2 * c2], w1 = ep[r * 96 + 2 * c2 + 1];
        XWp[node * 24 + c2] = pack_bf2(w0, w1);
        float v0 = ep[r * 96 + 48 + 2 * c2], v1 = ep[r * 96 + 48 + 2 * c2 + 1];
        float2 bb = ((const float2*)b)[c2];
        AGGp[node * 24 + c2] = pack_bf2(v0 + bb.x, v1 + bb.y);
    }
}

// ---- phase A: bin counting (LDS hist -> consecutive-addr atomics) + gemm1 --
__global__ __launch_bounds__(256) void count_gemm1(
    const int* __restrict__ dst, int* __restrict__ binCnt, int E, int nCountBlocks,
    const float* __restrict__ X, const float* __restrict__ W,
    const float* __restrict__ V, const float* __restrict__ b,
    unsigned* __restrict__ XWp, unsigned* __restrict__ AGGp, int N) {
    __shared__ char smem[36864];
    if ((int)blockIdx.x < nCountBlocks) {
        int* hist = (int*)smem;
        int tid = threadIdx.x;
        hist[tid] = 0;
        __syncthreads();
        long long e0 = (long long)blockIdx.x * CHUNK;
        int M = (int)min((long long)CHUNK, (long long)E - e0);
        for (int i = tid; i < M; i += 256) atomicAdd(&hist[dst[e0 + i] >> BIN_SHIFT], 1);
        __syncthreads();
        atomicAdd(&binCnt[tid], hist[tid]);  // consecutive words -> coalesced
    } else {
        mfma_gemm1_body(smem, X, W, V, b, XWp, AGGp, N,
                        (int)blockIdx.x - nCountBlocks, (int)threadIdx.x);
    }
}

// ---- phase B: exclusive scan of 256 bin counts -----------------------------
__global__ void scan_bins(const int* __restrict__ binCnt, int* __restrict__ binStart,
                          int* __restrict__ binCursor, int* __restrict__ rowPtr,
                          int E, int N) {
    __shared__ int s[256];
    int t = threadIdx.x;
    int v = binCnt[t];
    s[t] = v;
    __syncthreads();
#pragma unroll
    for (int o = 1; o < 256; o <<= 1) {
        int u = (t >= o) ? s[t - o] : 0;
        __syncthreads();
        s[t] += u;
        __syncthreads();
    }
    int excl = s[t] - v;
    binStart[t] = excl;
    binCursor[t] = excl;
    if (t == 0) {
        binStart[256] = E;
        rowPtr[N] = E;
    }
}

// ---- phase C: scatter edges into bin regions (256B runs, line-coalesced) ---
__global__ void binscatter(const int* __restrict__ src, const int* __restrict__ dst,
                           const float* __restrict__ w, int* __restrict__ binCursor,
                           int2* __restrict__ binned, int E) {
    __shared__ int sx[CHUNK];
    __shared__ int sw[CHUNK];
    __shared__ unsigned char sbin[CHUNK];
    __shared__ int hist[256];
    int tid = threadIdx.x;
    hist[tid] = 0;
    __syncthreads();
    long long e0 = (long long)blockIdx.x * CHUNK;
    int M = (int)min((long long)CHUNK, (long long)E - e0);
    for (int i = tid; i < M; i += 256) {
        int d = dst[e0 + i];
        int bn = d >> BIN_SHIFT;
        sx[i] = ((d & 511) << 17) | src[e0 + i];
        sw[i] = __float_as_int(w[e0 + i]);
        sbin[i] = (unsigned char)bn;
        atomicAdd(&hist[bn], 1);
    }
    __syncthreads();
    int base = atomicAdd(&binCursor[tid], hist[tid]);  // consecutive words -> coalesced
    __syncthreads();
    hist[tid] = base;  // reuse as global cursor
    __syncthreads();
    for (int i = tid; i < M; i += 256) {
        int p = atomicAdd(&hist[sbin[i]], 1);  // LDS atomic, cheap
        binned[p] = make_int2(sx[i], sw[i]);
    }
}

// ---- phase D: per-bin LDS counting sort -> compressed 4B CSR ---------------
// csr[e] = (src:17 << 15) | bf15(w * dinv[dst])  (w*dinv > 0, sign dropped)
__global__ __launch_bounds__(512) void build_csr(const int2* __restrict__ binned,
                                                 const int* __restrict__ binStart,
                                                 int* __restrict__ rowPtr,
                                                 float* __restrict__ dinv,
                                                 unsigned* __restrict__ csr, int N) {
    __shared__ int sx[CSR_CAP];
    __shared__ int sw[CSR_CAP];
    __shared__ int cntL[512];
    __shared__ float degL[512];  // deg sums, then dinv values
    __shared__ int scanL[512];
    int b = blockIdx.x, tid = threadIdx.x;
    int e0 = binStart[b], e1 = binStart[b + 1], M = e1 - e0;
    cntL[tid] = 0;
    degL[tid] = 0.f;
    __syncthreads();
    bool fits = (M <= CSR_CAP);
    for (int i = tid; i < M; i += 512) {
        int2 p = binned[e0 + i];
        if (fits) { sx[i] = p.x; sw[i] = p.y; }
        int dl = ((unsigned)p.x) >> 17;
        atomicAdd(&cntL[dl], 1);
        atomicAdd(&degL[dl], __int_as_float(p.y));
    }
    __syncthreads();
    int v = cntL[tid];
    scanL[tid] = v;
    __syncthreads();
#pragma unroll
    for (int o = 1; o < 512; o <<= 1) {
        int u = (tid >= o) ? scanL[tid - o] : 0;
        __syncthreads();
        scanL[tid] += u;
        __syncthreads();
    }
    int excl = scanL[tid] - v;
    int node = (b << BIN_SHIFT) + tid;
    float dg = degL[tid];
    float dv = dg > 0.f ? rsqrtf(dg) : 0.f;
    if (node < N) {
        rowPtr[node] = e0 + excl;
        dinv[node] = dv;
    }
    cntL[tid] = e0 + excl;  // reuse as global write cursor
    degL[tid] = dv;         // reuse as dinv table for write phase
    __syncthreads();
    for (int i = tid; i < M; i += 512) {
        int px, pw;
        if (fits) { px = sx[i]; pw = sw[i]; }
        else { int2 p = binned[e0 + i]; px = p.x; pw = p.y; }
        int dl = ((unsigned)px) >> 17;
        int pos = atomicAdd(&cntL[dl], 1);  // LDS atomic
        float wn = __int_as_float(pw) * degL[dl];  // fold dinv[dst] in now
        unsigned uw = __float_as_uint(wn);
        uw = (uw + 0x7fffu + ((uw >> 16) & 1u)) >> 16;  // bf16 RNE; positive -> <=0x7FFF
        csr[pos] = ((unsigned)(px & 0x1FFFF) << 15) | uw;
    }
}

// ---- xWp[n][c2] *= dinv[n]  (layer-1) --------------------------------------
__global__ void scale_xw(unsigned* __restrict__ XWp, const float* __restrict__ dinv,
                         int total) {
    int t = blockIdx.x * blockDim.x + threadIdx.x;
    if (t >= total) return;
    float dv = dinv[t / 24];
    float2 u = unpack_bf2(XWp[t]);
    XWp[t] = pack_bf2(u.x * dv, u.y * dv);
}

// ---- row accumulate: 2 u32 cols/thread, aligned uint4 csr loads ------------
template <int W>
__device__ __forceinline__ float4 row_accum2(const unsigned* __restrict__ XWp,
                                             const unsigned* __restrict__ csr,
                                             int j, int end, int c, float4 s) {
    // head: scalar until j is 4-aligned (csr base is 256B-aligned)
    while (j < end && (j & 3)) {
        unsigned p = csr[j++];
        uint2 u = *(const uint2*)(XWp + (p >> 15) * W + c);
        float nr = __uint_as_float((p & 0x7FFFu) << 16);
        float2 x0 = unpack_bf2(u.x), x1 = unpack_bf2(u.y);
        s.x = fmaf(x0.x, nr, s.x); s.y = fmaf(x0.y, nr, s.y);
        s.z = fmaf(x1.x, nr, s.z); s.w = fmaf(x1.y, nr, s.w);
    }
    for (; j + 4 <= end; j += 4) {
        uint4 p4 = *(const uint4*)(csr + j);  // one dwordx4 per 4 edges
        uint2 u0 = *(const uint2*)(XWp + (p4.x >> 15) * W + c);
        uint2 u1 = *(const uint2*)(XWp + (p4.y >> 15) * W + c);
        uint2 u2 = *(const uint2*)(XWp + (p4.z >> 15) * W + c);
        uint2 u3 = *(const uint2*)(XWp + (p4.w >> 15) * W + c);
        float n0 = __uint_as_float((p4.x & 0x7FFFu) << 16);
        float n1 = __uint_as_float((p4.y & 0x7FFFu) << 16);
        float n2 = __uint_as_float((p4.z & 0x7FFFu) << 16);
        float n3 = __uint_as_float((p4.w & 0x7FFFu) << 16);
        float2 a0 = unpack_bf2(u0.x), b0 = unpack_bf2(u0.y);
        float2 a1 = unpack_bf2(u1.x), b1 = unpack_bf2(u1.y);
        float2 a2 = unpack_bf2(u2.x), b2 = unpack_bf2(u2.y);
        float2 a3 = unpack_bf2(u3.x), b3 = unpack_bf2(u3.y);
        s.x = fmaf(a0.x, n0, s.x); s.y = fmaf(a0.y, n0, s.y);
        s.z = fmaf(b0.x, n0, s.z); s.w = fmaf(b0.y, n0, s.w);
        s.x = fmaf(a1.x, n1, s.x); s.y = fmaf(a1.y, n1, s.y);
        s.z = fmaf(b1.x, n1, s.z); s.w = fmaf(b1.y, n1, s.w);
        s.x = fmaf(a2.x, n2, s.x); s.y = fmaf(a2.y, n2, s.y);
        s.z = fmaf(b2.x, n2, s.z); s.w = fmaf(b2.y, n2, s.w);
        s.x = fmaf(a3.x, n3, s.x); s.y = fmaf(a3.y, n3, s.y);
        s.z = fmaf(b3.x, n3, s.z); s.w = fmaf(b3.y, n3, s.w);
    }
    for (; j < end; ++j) {
        unsigned p = csr[j];
        uint2 u = *(const uint2*)(XWp + (p >> 15) * W + c);
        float nr = __uint_as_float((p & 0x7FFFu) << 16);
        float2 x0 = unpack_bf2(u.x), x1 = unpack_bf2(u.y);
        s.x = fmaf(x0.x, nr, s.x); s.y = fmaf(x0.y, nr, s.y);
        s.z = fmaf(x1.x, nr, s.z); s.w = fmaf(x1.y, nr, s.w);
    }
    return s;
}

// ---- layer-1 pull: h1[n] = relu(bf16(AGG1p[n]) + sum_j xWp[src_j]*nrm_j) ---
// 12 threads/node, 2 u32 cols each; block 384 = 32 nodes. Skinny: 0 LDS.
__global__ __launch_bounds__(384) void pull_agg(const unsigned* __restrict__ XWp,
                                                const unsigned* __restrict__ csr,
                                                const int* __restrict__ rowPtr,
                                                const unsigned* __restrict__ AGG1p,
                                                unsigned* __restrict__ H1p, int N) {
    int t = blockIdx.x * blockDim.x + threadIdx.x;
    int n = t / 12, c1 = t - n * 12;
    if (n >= N) return;
    int c = 2 * c1;
    uint2 a = *(const uint2*)(AGG1p + n * 24 + c);
    float2 f0 = unpack_bf2(a.x), f1 = unpack_bf2(a.y);
    float4 s = make_float4(f0.x, f0.y, f1.x, f1.y);
    s = row_accum2<24>(XWp, csr, rowPtr[n], rowPtr[n + 1], c, s);
    uint2 o;
    o.x = pack_bf2(fmaxf(s.x, 0.f), fmaxf(s.y, 0.f));
    o.y = pack_bf2(fmaxf(s.z, 0.f), fmaxf(s.w, 0.f));
    *(uint2*)(H1p + n * 24 + c) = o;  // relu'd bf16 h1
}

// ============================================================================
// MFMA layer-2 GEMM: 64 nodes/block, 80 cols (W2|V2), K=48 zero-padded to 64.
// A = h1 relu'd bf16 -> direct fragment loads. xW2p dinv-scaled; agg2 packed.
// ============================================================================
__global__ __launch_bounds__(256) void gemm2_kernel(
    const short* __restrict__ H1, const float* __restrict__ W,
    const float* __restrict__ V, const float* __restrict__ b,
    const float* __restrict__ dinv, unsigned* __restrict__ XWp,
    unsigned* __restrict__ AGGp, int N) {
    __shared__ char smem[30720];
    short* sWT = (short*)smem;            // [80][64], k>=48 zero
    float* ep = (float*)(smem + 10240);   // [64][80]
    int tid = threadIdx.x;
    for (int i = tid; i < 80 * 64; i += 256) {
        int c = i >> 6, k = i & 63;
        float v = 0.f;
        if (k < 48) v = (c < 40) ? W[k * 40 + c] : V[k * 40 + (c - 40)];
        sWT[i] = bfr(v);
    }
    __syncthreads();

    int lane = tid & 63, wv = tid >> 6;
    int m = lane & 15, quad = lane >> 4;
    int nb0 = (int)blockIdx.x * 64;
    int n = nb0 + wv * 16 + m;

    bf16x8 a0, a1;
    if (n < N) {
        a0 = *(const bf16x8*)(H1 + (size_t)n * 48 + quad * 8);
        if (quad < 2) {
            a1 = *(const bf16x8*)(H1 + (size_t)n * 48 + 32 + quad * 8);
        } else {
            for (int j = 0; j < 8; ++j) a1[j] = 0;
        }
    } else {
        for (int j = 0; j < 8; ++j) { a0[j] = 0; a1[j] = 0; }
    }

    f32x4 acc[5];
#pragma unroll
    for (int ct = 0; ct < 5; ++ct) acc[ct] = (f32x4){0.f, 0.f, 0.f, 0.f};
#pragma unroll
    for (int ct = 0; ct < 5; ++ct) {
        bf16x8 b0 = *(const bf16x8*)(sWT + (ct * 16 + m) * 64 + quad * 8);
        bf16x8 b1 = *(const bf16x8*)(sWT + (ct * 16 + m) * 64 + 32 + quad * 8);
        acc[ct] = __builtin_amdgcn_mfma_f32_16x16x32_bf16(a0, b0, acc[ct], 0, 0, 0);
        acc[ct] = __builtin_amdgcn_mfma_f32_16x16x32_bf16(a1, b1, acc[ct], 0, 0, 0);
    }
#pragma unroll
    for (int ct = 0; ct < 5; ++ct)
#pragma unroll
        for (int r = 0; r < 4; ++r)
            ep[(wv * 16 + quad * 4 + r) * 80 + ct * 16 + m] = acc[ct][r];
    __syncthreads();
    for (int i = tid; i < 64 * 20; i += 256) {
        int r = i / 20, c2 = i - r * 20;
        int node = nb0 + r;
        if (node >= N) continue;
        float dv = dinv[node];
        float w0 = ep[r * 80 + 2 * c2], w1 = ep[r * 80 + 2 * c2 + 1];
        XWp[node * 20 + c2] = pack_bf2(w0 * dv, w1 * dv);
        float v0 = ep[r * 80 + 40 + 2 * c2], v1 = ep[r * 80 + 40 + 2 * c2 + 1];
        float2 bb = ((const float2*)b)[c2];
        AGGp[node * 20 + c2] = pack_bf2(v0 + bb.x, v1 + bb.y);
    }
}

// ---- layer-2 pull fused with log_softmax(relu(.)) --------------------------
// block = 320 threads = 32 nodes x 10 threads (2 u32 cols each).
__global__ __launch_bounds__(320) void pull_ls(const unsigned* __restrict__ XWp,
                                               const unsigned* __restrict__ csr,
                                               const int* __restrict__ rowPtr,
                                               const unsigned* __restrict__ AGG2p,
                                               float* __restrict__ out, int N) {
    __shared__ float4 sbuf[32 * 10];
    __shared__ float sl[32];
    int tid = threadIdx.x;
    int nl = tid / 10, c1 = tid - nl * 10;
    int n = blockIdx.x * 32 + nl;
    int c = 2 * c1;
    float4 s = make_float4(0.f, 0.f, 0.f, 0.f);
    if (n < N) {
        uint2 a = *(const uint2*)(AGG2p + n * 20 + c);
        float2 f0 = unpack_bf2(a.x), f1 = unpack_bf2(a.y);
        s = make_float4(f0.x, f0.y, f1.x, f1.y);
        s = row_accum2<20>(XWp, csr, rowPtr[n], rowPtr[n + 1], c, s);
    }
    sbuf[nl * 10 + c1] = s;
    __syncthreads();
    if (tid < 32) {
        float m = 0.f;  // relu floor
        for (int k = 0; k < 10; ++k) {
            float4 v = sbuf[tid * 10 + k];
            m = fmaxf(m, fmaxf(fmaxf(v.x, v.y), fmaxf(v.z, v.w)));
        }
        float sum = 0.f;
        for (int k = 0; k < 10; ++k) {
            float4 v = sbuf[tid * 10 + k];
            sum += expf(fmaxf(v.x, 0.f) - m) + expf(fmaxf(v.y, 0.f) - m) +
                   expf(fmaxf(v.z, 0.f) - m) + expf(fmaxf(v.w, 0.f) - m);
        }
        sl[tid] = m + logf(sum);
    }
    __syncthreads();
    if (n < N) {
        float l = sl[nl];
        ((float4*)out)[n * 10 + c1] =
            make_float4(fmaxf(s.x, 0.f) - l, fmaxf(s.y, 0.f) - l,
                        fmaxf(s.z, 0.f) - l, fmaxf(s.w, 0.f) - l);
    }
}

extern "C" void kernel_launch(void* const* d_in, const int* in_sizes, int n_in,
                              void* d_out, int out_size, void* d_ws, size_t ws_size,
                              hipStream_t stream) {
    const float* x  = (const float*)d_in[0];
    const int*   ei = (const int*)d_in[1];
    const float* ew = (const float*)d_in[2];
    const float* W1 = (const float*)d_in[3];
    const float* V1 = (const float*)d_in[4];
    const float* b1 = (const float*)d_in[5];
    const float* W2 = (const float*)d_in[6];
    const float* V2 = (const float*)d_in[7];
    const float* b2 = (const float*)d_in[8];
    float* out = (float*)d_out;

    const int N = in_sizes[0] / F_IN;
    const int E = in_sizes[2];
    const int* src = ei;
    const int* dst = ei + E;

    char* ws = (char*)d_ws;
    size_t off = 0;
    auto carve = [&](size_t bytes) {
        void* p = ws + off;
        off = (off + bytes + 255) & ~size_t(255);
        return p;
    };
    int*      binCnt    = (int*)carve(256 * 4);
    int*      binStart  = (int*)carve(257 * 4);
    int*      binCursor = (int*)carve(256 * 4);
    int*      rowPtr    = (int*)carve((size_t)(N + 1) * 4);
    float*    dinv      = (float*)carve((size_t)N * 4);
    int2*     binned    = (int2*)carve((size_t)E * 8);
    unsigned* csr       = (unsigned*)carve((size_t)E * 4);        // compressed 4B
    unsigned* xW1p      = (unsigned*)carve((size_t)N * 24 * 4);   // bf16x2 flat
    unsigned* agg1p     = (unsigned*)carve((size_t)N * 24 * 4);   // bf16x2 V1-part
    unsigned* h1p       = (unsigned*)carve((size_t)N * 24 * 4);   // relu'd bf16 h1
    unsigned* xW2p      = (unsigned*)carve((size_t)N * 20 * 4);
    unsigned* agg2p     = (unsigned*)carve((size_t)N * 20 * 4);   // bf16x2 V2-part

    const int B = 256;
    auto cdiv = [](long long a, long long b) { return (int)((a + b - 1) / b); };
    const int nChunks = cdiv(E, CHUNK);
    const int nBins = (N + (1 << BIN_SHIFT) - 1) >> BIN_SHIFT;
    const int nGemmBlocks = cdiv(N, 64);

    hipMemsetAsync(binCnt, 0, 256 * 4, stream);

    count_gemm1<<<nChunks + nGemmBlocks, B, 0, stream>>>(dst, binCnt, E, nChunks,
                                                         x, W1, V1, b1, xW1p, agg1p, N);
    scan_bins<<<1, 256, 0, stream>>>(binCnt, binStart, binCursor, rowPtr, E, N);
    binscatter<<<nChunks, B, 0, stream>>>(src, dst, ew, binCursor, binned, E);
    build_csr<<<nBins, 512, 0, stream>>>(binned, binStart, rowPtr, dinv, csr, N);

    scale_xw<<<cdiv((long long)N * 24, B), B, 0, stream>>>(xW1p, dinv, N * 24);

    pull_agg<<<cdiv((long long)N * 12, 384), 384, 0, stream>>>(xW1p, csr, rowPtr,
                                                               agg1p, h1p, N);

    gemm2_kernel<<<nGemmBlocks, B, 0, stream>>>((const short*)h1p, W2, V2, b2,
                                                dinv, xW2p, agg2p, N);

    pull_ls<<<cdiv(N, 32), 320, 0, stream>>>(xW2p, csr, rowPtr, agg2p, out, N);
}